// Round 7
// baseline (241.631 us; speedup 1.0000x reference)
//
#include <hip/hip_runtime.h>
#include <math.h>

// Problem constants
#define BATCH 8
#define NN 64
#define DD 65536            // 64*32*32 feature length (contiguous per [b,n])
#define BPB 64              // blocks per batch -> grid = 512
#define NBLK (BATCH * BPB)
#define KC (DD / BPB)       // 1024 K per block
#define KW (KC / 4)         // 256 K per wave (waves split K)
#define KSTEPS (KW / 32)    // 8 MFMA K-steps per wave
#define NTRI 10             // upper-triangle 16x16 tiles of the 64x64 Gram
#define PSZ (NTRI * 256)    // floats per partial (2560)

typedef float  floatx4 __attribute__((ext_vector_type(4)));
typedef __bf16 bf16x8  __attribute__((ext_vector_type(8)));

// Pack 8 fp32 -> 8 bf16 via v_perm_b32 (truncation; bias cancels in the
// scale-invariant cosine ratio — validated: absmax 1.5e-5).
static __device__ __forceinline__ bf16x8 cvt8(float4 lo, float4 hi) {
    const unsigned sel = 0x07060302u;
    union { unsigned u[4]; bf16x8 v; } r;
    r.u[0] = __builtin_amdgcn_perm(__float_as_uint(lo.y), __float_as_uint(lo.x), sel);
    r.u[1] = __builtin_amdgcn_perm(__float_as_uint(lo.w), __float_as_uint(lo.z), sel);
    r.u[2] = __builtin_amdgcn_perm(__float_as_uint(hi.y), __float_as_uint(hi.x), sel);
    r.u[3] = __builtin_amdgcn_perm(__float_as_uint(hi.w), __float_as_uint(hi.z), sel);
    return r.v;
}

// ---------------------------------------------------------------------------
// Stage 1: verbatim R0 gram kernel (the 217.7 µs best). Dispatched TWICE
// this round (idempotent — identical partials written both times) as a
// duration probe: Δtotal vs R0 ≈ gram#2 + one launch gap, and gram shows up
// in the rocprof top-5 iff it exceeds the ~77 µs fill dispatches.
// ---------------------------------------------------------------------------
__global__ __launch_bounds__(256, 3) void gram_partial_kernel(const float* __restrict__ a,
                                                              float* __restrict__ part) {
    __shared__ __align__(16) float red[3][NTRI][64][4];   // 30 KB

    const int bid = blockIdx.x;
    const int b = bid >> 6;           // / BPB
    const int c = bid & (BPB - 1);

    const int tid  = threadIdx.x;
    const int w    = tid >> 6;        // wave id 0..3 -> K-subchunk
    const int lane = tid & 63;
    const int m    = lane & 15;
    const int q    = lane >> 4;

    const float* base = a + (size_t)b * NN * DD + (size_t)c * KC + (size_t)w * KW
                          + (size_t)m * DD + q * 8;
    const float* p0 = base;                       // rows  0..15
    const float* p1 = base + (size_t)16 * DD;     // rows 16..31
    const float* p2 = base + (size_t)32 * DD;     // rows 32..47
    const float* p3 = base + (size_t)48 * DD;     // rows 48..63

    floatx4 acc[NTRI];
    #pragma unroll
    for (int i = 0; i < NTRI; ++i) acc[i] = (floatx4)0.0f;

    float4 A0, A1, A2, A3, A4, A5, A6, A7;   // buffer A
    float4 B0, B1, B2, B3, B4, B5, B6, B7;   // buffer B

#define LOADSET(R0,R1,R2,R3,R4,R5,R6,R7, o)                                \
    R0 = *(const float4*)(p0 + (o));  R1 = *(const float4*)(p0 + (o) + 4); \
    R2 = *(const float4*)(p1 + (o));  R3 = *(const float4*)(p1 + (o) + 4); \
    R4 = *(const float4*)(p2 + (o));  R5 = *(const float4*)(p2 + (o) + 4); \
    R6 = *(const float4*)(p3 + (o));  R7 = *(const float4*)(p3 + (o) + 4);

    // acc slots: 0:(0,0) 1:(0,1) 2:(0,2) 3:(0,3) 4:(1,1) 5:(1,2) 6:(1,3)
    //            7:(2,2) 8:(2,3) 9:(3,3)
#define MFMASET(R0,R1,R2,R3,R4,R5,R6,R7)                                   \
    {                                                                      \
        bf16x8 f0 = cvt8(R0, R1);                                          \
        bf16x8 f1 = cvt8(R2, R3);                                          \
        bf16x8 f2 = cvt8(R4, R5);                                          \
        bf16x8 f3 = cvt8(R6, R7);                                          \
        acc[0] = __builtin_amdgcn_mfma_f32_16x16x32_bf16(f0, f0, acc[0], 0, 0, 0); \
        acc[1] = __builtin_amdgcn_mfma_f32_16x16x32_bf16(f0, f1, acc[1], 0, 0, 0); \
        acc[2] = __builtin_amdgcn_mfma_f32_16x16x32_bf16(f0, f2, acc[2], 0, 0, 0); \
        acc[3] = __builtin_amdgcn_mfma_f32_16x16x32_bf16(f0, f3, acc[3], 0, 0, 0); \
        acc[4] = __builtin_amdgcn_mfma_f32_16x16x32_bf16(f1, f1, acc[4], 0, 0, 0); \
        acc[5] = __builtin_amdgcn_mfma_f32_16x16x32_bf16(f1, f2, acc[5], 0, 0, 0); \
        acc[6] = __builtin_amdgcn_mfma_f32_16x16x32_bf16(f1, f3, acc[6], 0, 0, 0); \
        acc[7] = __builtin_amdgcn_mfma_f32_16x16x32_bf16(f2, f2, acc[7], 0, 0, 0); \
        acc[8] = __builtin_amdgcn_mfma_f32_16x16x32_bf16(f2, f3, acc[8], 0, 0, 0); \
        acc[9] = __builtin_amdgcn_mfma_f32_16x16x32_bf16(f3, f3, acc[9], 0, 0, 0); \
    }

    LOADSET(A0,A1,A2,A3,A4,A5,A6,A7, 0)
    #pragma unroll
    for (int s = 0; s < KSTEPS; s += 2) {
        LOADSET(B0,B1,B2,B3,B4,B5,B6,B7, (s + 1) * 32)
        MFMASET(A0,A1,A2,A3,A4,A5,A6,A7)
        if (s + 2 < KSTEPS) { LOADSET(A0,A1,A2,A3,A4,A5,A6,A7, (s + 2) * 32) }
        MFMASET(B0,B1,B2,B3,B4,B5,B6,B7)
    }
#undef LOADSET
#undef MFMASET

    // Cross-wave reduce: waves 1..3 dump accs to LDS; wave 0 sums + stores.
    if (w > 0) {
        #pragma unroll
        for (int t = 0; t < NTRI; ++t)
            *(floatx4*)&red[w - 1][t][lane][0] = acc[t];
    }
    __syncthreads();
    if (w == 0) {
        #pragma unroll
        for (int t = 0; t < NTRI; ++t) {
            floatx4 r0 = *(const floatx4*)&red[0][t][lane][0];
            floatx4 r1 = *(const floatx4*)&red[1][t][lane][0];
            floatx4 r2 = *(const floatx4*)&red[2][t][lane][0];
            acc[t] += (r0 + r1) + r2;
        }
        // slot t holds G[16*ib + 4q + r][16*jb + m] (m89 layout, validated)
        float* pg = part + (size_t)bid * PSZ;
        #pragma unroll
        for (int t = 0; t < NTRI; ++t) {
            float* tp = pg + t * 256 + m;
            #pragma unroll
            for (int r = 0; r < 4; ++r)
                tp[(q * 4 + r) * 16] = acc[t][r];
        }
    }
}

// ---------------------------------------------------------------------------
// Stage 2 (merged): reduce the 64 tri-partials of batch b AND run the CRF —
// one kernel, 8 blocks. The float4 column-reduce and tri->full expansion are
// the exact code validated inside R1's fused phase 3 (plain loads now: the
// partials come from a previous dispatch, so they are globally visible).
// Removes one launch + the gram[] global round-trip.
// ---------------------------------------------------------------------------
__global__ __launch_bounds__(256) void reduce_crf_kernel(const float* __restrict__ part,
                                                         const float* __restrict__ logits,
                                                         const float* __restrict__ Wm,
                                                         float* __restrict__ out) {
    __shared__ __align__(16) struct {
        float tri[PSZ];                   // reduced tri gram (10 KB)
        float G[NN][NN + 1];
        float E[NN];
        float nrm[NN];
        float part4[4 * NN];
    } sh;

    const int b   = blockIdx.x;
    const int tid = threadIdx.x;

    // Reduce 64 partials -> tri (640 float4 columns, vectorized).
    const float* pb = part + (size_t)b * BPB * PSZ;
    for (int fo = tid; fo < PSZ / 4; fo += 256) {
        float4 a0 = {0.f, 0.f, 0.f, 0.f}, a1 = a0, a2 = a0, a3 = a0;
        const float* p = pb + fo * 4;
        #pragma unroll 4
        for (int cc2 = 0; cc2 < BPB; cc2 += 4) {
            float4 v0 = *(const float4*)(p + (size_t)(cc2 + 0) * PSZ);
            float4 v1 = *(const float4*)(p + (size_t)(cc2 + 1) * PSZ);
            float4 v2 = *(const float4*)(p + (size_t)(cc2 + 2) * PSZ);
            float4 v3 = *(const float4*)(p + (size_t)(cc2 + 3) * PSZ);
            a0.x += v0.x; a0.y += v0.y; a0.z += v0.z; a0.w += v0.w;
            a1.x += v1.x; a1.y += v1.y; a1.z += v1.z; a1.w += v1.w;
            a2.x += v2.x; a2.y += v2.y; a2.z += v2.z; a2.w += v2.w;
            a3.x += v3.x; a3.y += v3.y; a3.z += v3.z; a3.w += v3.w;
        }
        float4 s;
        s.x = (a0.x + a1.x) + (a2.x + a3.x);
        s.y = (a0.y + a1.y) + (a2.y + a3.y);
        s.z = (a0.z + a1.z) + (a2.z + a3.z);
        s.w = (a0.w + a1.w) + (a2.w + a3.w);
        *(float4*)&sh.tri[fo * 4] = s;
    }
    __syncthreads();

    // Expand tri layout to full G (K-partial Grams are symmetric).
    for (int idx = tid; idx < NN * NN; idx += 256) {
        int i  = idx >> 6, j = idx & 63;
        int ti = i >> 4, tj = j >> 4;
        int ib = ti <= tj ? ti : tj;
        int jb = ti <= tj ? tj : ti;
        int slot = ib * 4 - (ib * (ib - 1)) / 2 + (jb - ib);
        int rr = (ti <= tj) ? (i & 15) : (j & 15);
        int cc = (ti <= tj) ? (j & 15) : (i & 15);
        sh.G[i][j] = sh.tri[slot * 256 + rr * 16 + cc];
    }
    __syncthreads();

    const int ci = tid & 63;
    const int jq = tid >> 6;

    if (jq == 0) sh.nrm[ci] = sqrtf(sh.G[ci][ci]);
    sh.E[ci] = 0.0f;
    __syncthreads();

    // pp in place: each (i,j) element owned by exactly one thread.
    const float ni = sh.nrm[ci];
    #pragma unroll
    for (int jj = 0; jj < 16; ++jj) {
        int j = jq * 16 + jj;
        float wsym = 0.5f * (Wm[ci * NN + j] + Wm[j * NN + ci]);
        sh.G[ci][j] = sh.G[ci][j] / (ni * sh.nrm[j] + 1e-6f) * wsym;
    }
    const float li = logits[b * NN + ci];
    __syncthreads();

    for (int it = 0; it < 10; ++it) {
        float acc2 = 0.0f;
        #pragma unroll
        for (int jj = 0; jj < 16; ++jj) {
            int j = jq * 16 + jj;
            float t = li + sh.E[j];
            float s = 1.0f / (1.0f + expf(-t));
            acc2 = fmaf(2.0f * s - 1.0f, sh.G[ci][j], acc2);
        }
        sh.part4[jq * NN + ci] = acc2;
        __syncthreads();
        if (jq == 0)
            sh.E[ci] = sh.part4[ci] + sh.part4[NN + ci]
                     + sh.part4[2 * NN + ci] + sh.part4[3 * NN + ci];
        __syncthreads();
    }

    if (tid < 64) {
        float s = sh.E[tid];
        for (int off = 32; off > 0; off >>= 1) s += __shfl_down(s, off);
        float meanE = __shfl(s, 0) * (1.0f / 64.0f);
        out[b * NN + tid] = logits[b * NN + tid] + meanE;
    }
}

extern "C" void kernel_launch(void* const* d_in, const int* in_sizes, int n_in,
                              void* d_out, int out_size, void* d_ws, size_t ws_size,
                              hipStream_t stream) {
    const float* a      = (const float*)d_in[0];  // [8,64,64,32,32]
    const float* logits = (const float*)d_in[1];  // [8,64]
    const float* Wm     = (const float*)d_in[2];  // [1,64,64]
    float* out  = (float*)d_out;                  // [8,64]

    float* part = (float*)d_ws;                   // [512][2560] fp32

    // PROBE ROUND: gram dispatched twice (idempotent). Dur delta vs the
    // single-dispatch shell measures gram's true duration + one launch gap;
    // top-5 visibility (vs the 77 µs fills) and the #1-vs-#2 split (L3-hot
    // second pass) disambiguate the cold-read-floor vs fixed-overhead worlds.
    gram_partial_kernel<<<NBLK, 256, 0, stream>>>(a, part);
    gram_partial_kernel<<<NBLK, 256, 0, stream>>>(a, part);
    reduce_crf_kernel<<<BATCH, 256, 0, stream>>>(part, logits, Wm, out);
}

// Round 8
// 218.566 us; speedup vs baseline: 1.1055x; 1.1055x over previous
//
#include <hip/hip_runtime.h>
#include <math.h>

// Problem constants
#define BATCH 8
#define NN 64
#define DD 65536            // 64*32*32 feature length (contiguous per [b,n])
#define BPB 64              // blocks per batch -> grid = 512
#define NBLK (BATCH * BPB)
#define KC (DD / BPB)       // 1024 K per block
#define KW (KC / 4)         // 256 K per wave (waves split K)
#define KSTEPS (KW / 32)    // 8 MFMA K-steps per wave
#define NTRI 10             // upper-triangle 16x16 tiles of the 64x64 Gram
#define PSZ (NTRI * 256)    // floats per partial (2560)

typedef float  floatx4 __attribute__((ext_vector_type(4)));
typedef __bf16 bf16x8  __attribute__((ext_vector_type(8)));

// Pack 8 fp32 -> 8 bf16 via v_perm_b32 (truncation; bias cancels in the
// scale-invariant cosine ratio — validated: absmax 1.5e-5).
static __device__ __forceinline__ bf16x8 cvt8(float4 lo, float4 hi) {
    const unsigned sel = 0x07060302u;
    union { unsigned u[4]; bf16x8 v; } r;
    r.u[0] = __builtin_amdgcn_perm(__float_as_uint(lo.y), __float_as_uint(lo.x), sel);
    r.u[1] = __builtin_amdgcn_perm(__float_as_uint(lo.w), __float_as_uint(lo.z), sel);
    r.u[2] = __builtin_amdgcn_perm(__float_as_uint(hi.y), __float_as_uint(hi.x), sel);
    r.u[3] = __builtin_amdgcn_perm(__float_as_uint(hi.w), __float_as_uint(hi.z), sel);
    return r.v;
}

// ---------------------------------------------------------------------------
// Stage 1: verbatim R0 gram kernel (validated across R0/R3/R7; measured
// ~28 µs by the R7 double-dispatch probe — ~75% of achievable copy BW for
// its 134 MB cold read).
// ---------------------------------------------------------------------------
__global__ __launch_bounds__(256, 3) void gram_partial_kernel(const float* __restrict__ a,
                                                              float* __restrict__ part) {
    __shared__ __align__(16) float red[3][NTRI][64][4];   // 30 KB

    const int bid = blockIdx.x;
    const int b = bid >> 6;           // / BPB
    const int c = bid & (BPB - 1);

    const int tid  = threadIdx.x;
    const int w    = tid >> 6;        // wave id 0..3 -> K-subchunk
    const int lane = tid & 63;
    const int m    = lane & 15;
    const int q    = lane >> 4;

    const float* base = a + (size_t)b * NN * DD + (size_t)c * KC + (size_t)w * KW
                          + (size_t)m * DD + q * 8;
    const float* p0 = base;                       // rows  0..15
    const float* p1 = base + (size_t)16 * DD;     // rows 16..31
    const float* p2 = base + (size_t)32 * DD;     // rows 32..47
    const float* p3 = base + (size_t)48 * DD;     // rows 48..63

    floatx4 acc[NTRI];
    #pragma unroll
    for (int i = 0; i < NTRI; ++i) acc[i] = (floatx4)0.0f;

    float4 A0, A1, A2, A3, A4, A5, A6, A7;   // buffer A
    float4 B0, B1, B2, B3, B4, B5, B6, B7;   // buffer B

#define LOADSET(R0,R1,R2,R3,R4,R5,R6,R7, o)                                \
    R0 = *(const float4*)(p0 + (o));  R1 = *(const float4*)(p0 + (o) + 4); \
    R2 = *(const float4*)(p1 + (o));  R3 = *(const float4*)(p1 + (o) + 4); \
    R4 = *(const float4*)(p2 + (o));  R5 = *(const float4*)(p2 + (o) + 4); \
    R6 = *(const float4*)(p3 + (o));  R7 = *(const float4*)(p3 + (o) + 4);

    // acc slots: 0:(0,0) 1:(0,1) 2:(0,2) 3:(0,3) 4:(1,1) 5:(1,2) 6:(1,3)
    //            7:(2,2) 8:(2,3) 9:(3,3)
#define MFMASET(R0,R1,R2,R3,R4,R5,R6,R7)                                   \
    {                                                                      \
        bf16x8 f0 = cvt8(R0, R1);                                          \
        bf16x8 f1 = cvt8(R2, R3);                                          \
        bf16x8 f2 = cvt8(R4, R5);                                          \
        bf16x8 f3 = cvt8(R6, R7);                                          \
        acc[0] = __builtin_amdgcn_mfma_f32_16x16x32_bf16(f0, f0, acc[0], 0, 0, 0); \
        acc[1] = __builtin_amdgcn_mfma_f32_16x16x32_bf16(f0, f1, acc[1], 0, 0, 0); \
        acc[2] = __builtin_amdgcn_mfma_f32_16x16x32_bf16(f0, f2, acc[2], 0, 0, 0); \
        acc[3] = __builtin_amdgcn_mfma_f32_16x16x32_bf16(f0, f3, acc[3], 0, 0, 0); \
        acc[4] = __builtin_amdgcn_mfma_f32_16x16x32_bf16(f1, f1, acc[4], 0, 0, 0); \
        acc[5] = __builtin_amdgcn_mfma_f32_16x16x32_bf16(f1, f2, acc[5], 0, 0, 0); \
        acc[6] = __builtin_amdgcn_mfma_f32_16x16x32_bf16(f1, f3, acc[6], 0, 0, 0); \
        acc[7] = __builtin_amdgcn_mfma_f32_16x16x32_bf16(f2, f2, acc[7], 0, 0, 0); \
        acc[8] = __builtin_amdgcn_mfma_f32_16x16x32_bf16(f2, f3, acc[8], 0, 0, 0); \
        acc[9] = __builtin_amdgcn_mfma_f32_16x16x32_bf16(f3, f3, acc[9], 0, 0, 0); \
    }

    LOADSET(A0,A1,A2,A3,A4,A5,A6,A7, 0)
    #pragma unroll
    for (int s = 0; s < KSTEPS; s += 2) {
        LOADSET(B0,B1,B2,B3,B4,B5,B6,B7, (s + 1) * 32)
        MFMASET(A0,A1,A2,A3,A4,A5,A6,A7)
        if (s + 2 < KSTEPS) { LOADSET(A0,A1,A2,A3,A4,A5,A6,A7, (s + 2) * 32) }
        MFMASET(B0,B1,B2,B3,B4,B5,B6,B7)
    }
#undef LOADSET
#undef MFMASET

    // Cross-wave reduce: waves 1..3 dump accs to LDS; wave 0 sums + stores.
    if (w > 0) {
        #pragma unroll
        for (int t = 0; t < NTRI; ++t)
            *(floatx4*)&red[w - 1][t][lane][0] = acc[t];
    }
    __syncthreads();
    if (w == 0) {
        #pragma unroll
        for (int t = 0; t < NTRI; ++t) {
            floatx4 r0 = *(const floatx4*)&red[0][t][lane][0];
            floatx4 r1 = *(const floatx4*)&red[1][t][lane][0];
            floatx4 r2 = *(const floatx4*)&red[2][t][lane][0];
            acc[t] += (r0 + r1) + r2;
        }
        // slot t holds G[16*ib + 4q + r][16*jb + m] (m89 layout, validated)
        float* pg = part + (size_t)bid * PSZ;
        #pragma unroll
        for (int t = 0; t < NTRI; ++t) {
            float* tp = pg + t * 256 + m;
            #pragma unroll
            for (int r = 0; r < 4; ++r)
                tp[(q * 4 + r) * 16] = acc[t][r];
        }
    }
}

// ---------------------------------------------------------------------------
// Stage 2 (merged): reduce the 64 tri-partials of batch b AND run the CRF —
// one kernel, 8 blocks (validated in R7 at absmax 1.525879e-05).
// ---------------------------------------------------------------------------
__global__ __launch_bounds__(256) void reduce_crf_kernel(const float* __restrict__ part,
                                                         const float* __restrict__ logits,
                                                         const float* __restrict__ Wm,
                                                         float* __restrict__ out) {
    __shared__ __align__(16) struct {
        float tri[PSZ];                   // reduced tri gram (10 KB)
        float G[NN][NN + 1];
        float E[NN];
        float nrm[NN];
        float part4[4 * NN];
    } sh;

    const int b   = blockIdx.x;
    const int tid = threadIdx.x;

    // Reduce 64 partials -> tri (640 float4 columns, vectorized).
    const float* pb = part + (size_t)b * BPB * PSZ;
    for (int fo = tid; fo < PSZ / 4; fo += 256) {
        float4 a0 = {0.f, 0.f, 0.f, 0.f}, a1 = a0, a2 = a0, a3 = a0;
        const float* p = pb + fo * 4;
        #pragma unroll 4
        for (int cc2 = 0; cc2 < BPB; cc2 += 4) {
            float4 v0 = *(const float4*)(p + (size_t)(cc2 + 0) * PSZ);
            float4 v1 = *(const float4*)(p + (size_t)(cc2 + 1) * PSZ);
            float4 v2 = *(const float4*)(p + (size_t)(cc2 + 2) * PSZ);
            float4 v3 = *(const float4*)(p + (size_t)(cc2 + 3) * PSZ);
            a0.x += v0.x; a0.y += v0.y; a0.z += v0.z; a0.w += v0.w;
            a1.x += v1.x; a1.y += v1.y; a1.z += v1.z; a1.w += v1.w;
            a2.x += v2.x; a2.y += v2.y; a2.z += v2.z; a2.w += v2.w;
            a3.x += v3.x; a3.y += v3.y; a3.z += v3.z; a3.w += v3.w;
        }
        float4 s;
        s.x = (a0.x + a1.x) + (a2.x + a3.x);
        s.y = (a0.y + a1.y) + (a2.y + a3.y);
        s.z = (a0.z + a1.z) + (a2.z + a3.z);
        s.w = (a0.w + a1.w) + (a2.w + a3.w);
        *(float4*)&sh.tri[fo * 4] = s;
    }
    __syncthreads();

    // Expand tri layout to full G (K-partial Grams are symmetric).
    for (int idx = tid; idx < NN * NN; idx += 256) {
        int i  = idx >> 6, j = idx & 63;
        int ti = i >> 4, tj = j >> 4;
        int ib = ti <= tj ? ti : tj;
        int jb = ti <= tj ? tj : ti;
        int slot = ib * 4 - (ib * (ib - 1)) / 2 + (jb - ib);
        int rr = (ti <= tj) ? (i & 15) : (j & 15);
        int cc = (ti <= tj) ? (j & 15) : (i & 15);
        sh.G[i][j] = sh.tri[slot * 256 + rr * 16 + cc];
    }
    __syncthreads();

    const int ci = tid & 63;
    const int jq = tid >> 6;

    if (jq == 0) sh.nrm[ci] = sqrtf(sh.G[ci][ci]);
    sh.E[ci] = 0.0f;
    __syncthreads();

    // pp in place: each (i,j) element owned by exactly one thread.
    const float ni = sh.nrm[ci];
    #pragma unroll
    for (int jj = 0; jj < 16; ++jj) {
        int j = jq * 16 + jj;
        float wsym = 0.5f * (Wm[ci * NN + j] + Wm[j * NN + ci]);
        sh.G[ci][j] = sh.G[ci][j] / (ni * sh.nrm[j] + 1e-6f) * wsym;
    }
    const float li = logits[b * NN + ci];
    __syncthreads();

    for (int it = 0; it < 10; ++it) {
        float acc2 = 0.0f;
        #pragma unroll
        for (int jj = 0; jj < 16; ++jj) {
            int j = jq * 16 + jj;
            float t = li + sh.E[j];
            float s = 1.0f / (1.0f + expf(-t));
            acc2 = fmaf(2.0f * s - 1.0f, sh.G[ci][j], acc2);
        }
        sh.part4[jq * NN + ci] = acc2;
        __syncthreads();
        if (jq == 0)
            sh.E[ci] = sh.part4[ci] + sh.part4[NN + ci]
                     + sh.part4[2 * NN + ci] + sh.part4[3 * NN + ci];
        __syncthreads();
    }

    if (tid < 64) {
        float s = sh.E[tid];
        for (int off = 32; off > 0; off >>= 1) s += __shfl_down(s, off);
        float meanE = __shfl(s, 0) * (1.0f / 64.0f);
        out[b * NN + tid] = logits[b * NN + tid] + meanE;
    }
}

extern "C" void kernel_launch(void* const* d_in, const int* in_sizes, int n_in,
                              void* d_out, int out_size, void* d_ws, size_t ws_size,
                              hipStream_t stream) {
    const float* a      = (const float*)d_in[0];  // [8,64,64,32,32]
    const float* logits = (const float*)d_in[1];  // [8,64]
    const float* Wm     = (const float*)d_in[2];  // [1,64,64]
    float* out  = (float*)d_out;                  // [8,64]

    float* part = (float*)d_ws;                   // [512][2560] fp32

    gram_partial_kernel<<<NBLK, 256, 0, stream>>>(a, part);
    reduce_crf_kernel<<<BATCH, 256, 0, stream>>>(part, logits, Wm, out);
}